// Round 12
// baseline (1827.501 us; speedup 1.0000x reference)
//
#include <hip/hip_runtime.h>
#include <hip/hip_fp16.h>
#include <math.h>

#define NT      1024
#define NPIX    16384
#define NSLICES 8
#define NMODES  4
#define OBJW    512

typedef float v2f __attribute__((ext_vector_type(2)));

// ---- packed fp32 complex primitives (VOP3P) --------------------------------
__device__ __forceinline__ v2f pk_add(v2f a, v2f b) {
    v2f d; asm("v_pk_add_f32 %0, %1, %2" : "=v"(d) : "v"(a), "v"(b)); return d;
}
__device__ __forceinline__ v2f pk_sub(v2f a, v2f b) {
    v2f d; asm("v_pk_add_f32 %0, %1, %2 neg_lo:[0,1] neg_hi:[0,1]"
               : "=v"(d) : "v"(a), "v"(b)); return d;
}
__device__ __forceinline__ v2f pk_fma(v2f a, v2f b, v2f c) {
    v2f d; asm("v_pk_fma_f32 %0, %1, %2, %3" : "=v"(d) : "v"(a), "v"(b), "v"(c)); return d;
}
// d = a*b (complex)
__device__ __forceinline__ v2f pk_cmul(v2f a, v2f b) {
    v2f t, d;
    asm("v_pk_mul_f32 %0, %1, %2 op_sel:[0,0] op_sel_hi:[1,0]"
        : "=v"(t) : "v"(a), "v"(b));
    asm("v_pk_fma_f32 %0, %1, %2, %3 op_sel:[1,1,0] op_sel_hi:[0,1,1] neg_lo:[1,0,0]"
        : "=v"(d) : "v"(a), "v"(b), "v"(t));
    return d;
}
// d = a*conj(b)
__device__ __forceinline__ v2f pk_cmulc(v2f a, v2f b) {
    v2f t, d;
    asm("v_pk_mul_f32 %0, %1, %2 op_sel:[0,0] op_sel_hi:[1,0]"
        : "=v"(t) : "v"(a), "v"(b));
    asm("v_pk_fma_f32 %0, %1, %2, %3 op_sel:[1,1,0] op_sel_hi:[0,1,1] neg_hi:[1,0,0]"
        : "=v"(d) : "v"(a), "v"(b), "v"(t));
    return d;
}
__device__ __forceinline__ v2f pk_mnegi(v2f a) { return (v2f){a.y, -a.x}; }  // a * -i
__device__ __forceinline__ v2f pk_mposi(v2f a) { return (v2f){-a.y, a.x}; }  // a * +i

// 4-bit reversal (constexpr -> folds to literals in unrolled loops)
__host__ __device__ constexpr int BR4(int p) {
    return ((p & 1) << 3) | ((p & 2) << 1) | ((p & 4) >> 1) | ((p & 8) >> 3);
}
__host__ __device__ constexpr int BR3(int c) {
    return ((c & 1) << 2) | (c & 2) | ((c & 4) >> 2);
}

// ---- compile-time sincos (double Taylor, |x|<=pi/2 after reduction) --------
constexpr double CPI = 3.14159265358979323846;
constexpr double TS(double x) {   // sin, |x|<=pi/2, err ~1e-9
    double x2 = x * x;
    return x*(1.0 - x2/6.0*(1.0 - x2/20.0*(1.0 - x2/42.0*
           (1.0 - x2/72.0*(1.0 - x2/110.0*(1.0 - x2/156.0))))));
}
constexpr double TC(double x) {   // cos, |x|<=pi/2, err ~1e-9
    double x2 = x * x;
    return 1.0 - x2/2.0*(1.0 - x2/12.0*(1.0 - x2/30.0*
           (1.0 - x2/56.0*(1.0 - x2/90.0*(1.0 - x2/132.0)))));
}
constexpr double S128(int k) {    // sin(2*pi*k/128)
    k %= 128; if (k < 0) k += 128;
    if (k < 32)  return  TS(CPI * k / 64.0);
    if (k < 64)  return  TS(CPI * (64 - k) / 64.0);
    if (k < 96)  return -TS(CPI * (k - 64) / 64.0);
    return -TS(CPI * (128 - k) / 64.0);
}
constexpr double C128(int k) { return S128(k + 32); }

struct alignas(8) CV { float x, y; };
struct Tab128 { CV e[128]; };

constexpr Tab128 genTA() {        // tA[8p+c] = W128^(jc*BR4(p)), e^{-i}
    Tab128 t{};
    for (int e = 0; e < 128; e++) {
        int p = e >> 3, c = e & 7;
        int jc = (c < 4) ? c : 11 - c;
        int m = jc * BR4(p);
        t.e[e] = CV{(float)C128(m), (float)(-S128(m))};
    }
    return t;
}
constexpr Tab128 genTB() {        // tB[8i+c] = W128^(i*br3(jc)), e^{-i}
    Tab128 t{};
    for (int e = 0; e < 128; e++) {
        int p = e >> 3, c = e & 7;
        int jc = (c < 4) ? c : 11 - c;
        int m = p * BR3(jc);
        t.e[e] = CV{(float)C128(m), (float)(-S128(m))};
    }
    return t;
}
constexpr Tab128 genPY() {        // pytp[8p+c], kh=br3(jc)+8BR4(p), /16384
    Tab128 t{};
    for (int e = 0; e < 128; e++) {
        int p = e >> 3, c = e & 7;
        int jc = (c < 4) ? c : 11 - c;
        int kh = BR3(jc) + 8 * BR4(p);
        double fy = (double)(kh < 64 ? kh : kh - 128) / 25.6;
        double ph = -(CPI / 20.0) * fy * fy;    // in [-0.982, 0] -> direct Taylor
        t.e[e] = CV{(float)(TC(ph) / 16384.0), (float)(TS(ph) / 16384.0)};
    }
    return t;
}
__device__ __constant__ Tab128 TA_C = genTA();
__device__ __constant__ Tab128 TB_C = genTB();
__device__ __constant__ Tab128 PY_C = genPY();

__device__ __forceinline__ v2f ldv(const CV* p) { return (v2f){p->x, p->y}; }

// ---- lane exchange primitives: ALL DPP (full-rate VALU, zero LDS pipe) -----
__device__ __forceinline__ float xor1f(float x) {
    int i = __float_as_int(x);
    return __int_as_float(__builtin_amdgcn_update_dpp(i, i, 0xB1, 0xF, 0xF, false));
}
__device__ __forceinline__ float xor2f(float x) {
    int i = __float_as_int(x);
    return __int_as_float(__builtin_amdgcn_update_dpp(i, i, 0x4E, 0xF, 0xF, false));
}
__device__ __forceinline__ float xor7f(float x) {
    int i = __float_as_int(x);
    return __int_as_float(__builtin_amdgcn_update_dpp(i, i, 0x141, 0xF, 0xF, false));
}

// relabeled stage-A twiddle fA'(lane) = lane<4 ? 1 : W8^(7-lane)
__device__ __constant__ float FA2_RE[8] = {1,1,1,1, -0.707106781f,  0.0f, 0.707106781f, 1.0f};
__device__ __constant__ float FA2_IM[8] = {0,0,0,0, -0.707106781f, -1.0f,-0.707106781f, 0.0f};

// ---- local 16-point FFT in registers (r2-proven codegen) -------------------
__device__ __forceinline__ void fft16_fwd(v2f v[16], const v2f* W) {
    #pragma unroll
    for (int s = 8; s >= 1; s >>= 1) {
        #pragma unroll
        for (int q = 0; q < 16; q += 2 * s) {
            #pragma unroll
            for (int j = 0; j < s; j++) {
                const int tw = j * (8 / s);
                v2f u = v[q + j], w = v[q + j + s];
                v[q + j] = pk_add(u, w);
                v2f d = pk_sub(u, w);
                v[q + j + s] = (tw == 0) ? d
                             : (tw == 4) ? pk_mnegi(d)
                                         : pk_cmulc(d, W[tw]);
            }
        }
    }
}
__device__ __forceinline__ void fft16_inv(v2f v[16], const v2f* W) {
    #pragma unroll
    for (int s = 1; s <= 8; s <<= 1) {
        #pragma unroll
        for (int q = 0; q < 16; q += 2 * s) {
            #pragma unroll
            for (int j = 0; j < s; j++) {
                const int tw = j * (8 / s);
                v2f u = v[q + j], w = v[q + j + s];
                v2f tv = (tw == 0) ? w
                       : (tw == 4) ? pk_mposi(w)
                                   : pk_cmul(w, W[tw]);
                v[q + j]     = pk_add(u, tv);
                v[q + j + s] = pk_sub(u, tv);
            }
        }
    }
}

// ---- cross-thread DFT8 over logical j (exchanges xor7, xor2, xor1) ---------
__device__ __forceinline__ void cross8_fwd(v2f v[16], v2f sAp, v2f sBp, v2f sCp,
                                           v2f fA, v2f rrf) {
    #pragma unroll
    for (int p = 0; p < 16; p++) {
        v2f o;
        o.x = xor7f(v[p].x); o.y = xor7f(v[p].y);
        v2f a = pk_fma(sAp, v[p], o);
        v2f b = pk_cmul(a, fA);
        o.x = xor2f(b.x); o.y = xor2f(b.y);
        v2f n = pk_fma(sBp, b, o);
        v2f r = pk_cmul(n, rrf);
        o.x = xor1f(r.x); o.y = xor1f(r.y);
        v[p] = pk_fma(sCp, r, o);
    }
}
__device__ __forceinline__ void cross8_inv(v2f v[16], v2f sAp, v2f sBp, v2f sCp,
                                           v2f fA, v2f rrf) {
    #pragma unroll
    for (int p = 0; p < 16; p++) {
        v2f o;
        o.x = xor1f(v[p].x); o.y = xor1f(v[p].y);
        v2f n = pk_fma(sCp, v[p], o);
        v2f r = pk_cmulc(n, rrf);
        o.x = xor2f(r.x); o.y = xor2f(r.y);
        v2f b = pk_fma(sBp, r, o);
        v2f a = pk_cmulc(b, fA);
        o.x = xor7f(a.x); o.y = xor7f(a.y);
        v[p] = pk_fma(sAp, a, o);
    }
}

// ---- passes; twiddle tables from __constant__ (index 8p+c / 8i+c) ----------
__device__ __forceinline__ void pass_A_fwd(v2f v[16], int c, v2f sAp, v2f sBp,
                                           v2f sCp, v2f fA, v2f rrf,
                                           const v2f* W) {
    fft16_fwd(v, W);
    #pragma unroll
    for (int p = 0; p < 16; p++) v[p] = pk_cmul(v[p], ldv(&TA_C.e[8 * p + c]));
    cross8_fwd(v, sAp, sBp, sCp, fA, rrf);
}
__device__ __forceinline__ void pass_A_inv(v2f v[16], int c, v2f sAp, v2f sBp,
                                           v2f sCp, v2f fA, v2f rrf,
                                           const v2f* W) {
    cross8_inv(v, sAp, sBp, sCp, fA, rrf);
    #pragma unroll
    for (int p = 0; p < 16; p++) v[p] = pk_cmulc(v[p], ldv(&TA_C.e[8 * p + c]));
    fft16_inv(v, W);
}
__device__ __forceinline__ void pass_B_fwd(v2f v[16], int c, v2f sAp, v2f sBp,
                                           v2f sCp, v2f fA, v2f rrf,
                                           const v2f* W) {
    cross8_fwd(v, sAp, sBp, sCp, fA, rrf);
    #pragma unroll
    for (int i = 0; i < 16; i++) v[i] = pk_cmul(v[i], ldv(&TB_C.e[8 * i + c]));
    fft16_fwd(v, W);
}
__device__ __forceinline__ void pass_B_inv(v2f v[16], int c, v2f sAp, v2f sBp,
                                           v2f sCp, v2f fA, v2f rrf,
                                           const v2f* W) {
    fft16_inv(v, W);
    #pragma unroll
    for (int i = 0; i < 16; i++) v[i] = pk_cmulc(v[i], ldv(&TB_C.e[8 * i + c]));
    cross8_inv(v, sAp, sBp, sCp, fA, rrf);
}

// ---- conversions -----------------------------------------------------------
__device__ __forceinline__ __half2 toh2(v2f a) {
    return __float22half2_rn(make_float2(a.x, a.y));
}
__device__ __forceinline__ v2f frh2(__half2 h) {
    float2 f = __half22float2(h);
    return (v2f){f.x, f.y};
}

// ---- main kernel: r9 structure; 64KiB LDS exactly --------------------------
// Transpose buffer at stride 128 (no pad) with XOR swizzle
//   phys(maj,min) = maj*128 + (min ^ (8*(maj&3)))
// Consistency: the swizzle term depends only on (maj, min); writer and reader
// of an element share maj (T1: kw&3=BR4(p)&3 vs g&3; T2: i&3 vs g&3), so the
// layout is bijective and read-back-correct. Banking: all four phases give 32
// distinct banks x 2 lanes (free floor).
// Twiddle tables (tA/tB/pytp) live in __constant__ (constexpr-generated).
// LDS = 65536 B: decisive test of the 128KiB-combined co-residency hypothesis
// (r5: 2x72704 no; r10: 2x69632 no; here 2x65536 = 131072).
__global__ void
__attribute__((amdgpu_flat_work_group_size(1024, 1024)))
multislice_kernel(const float* __restrict__ probe_re,
                  const float* __restrict__ probe_im,
                  const float* __restrict__ obj_re,
                  const float* __restrict__ obj_im,
                  const int*   __restrict__ positions,
                  float*       __restrict__ out)
{
    __shared__ __half2 LTH[128 * 128];   // 65536 B exactly

    const int t  = threadIdx.x;
    const int g  = t >> 3;                      // row (R) / col (C) index
    const int c  = t & 7;
    const int jc  = (c < 4) ? c : 11 - c;       // logical sub-index this lane holds
    const int rcp = BR3(jc);                    // frequency sub-index after cross8
    const int gh = g >> 4;                      // sigma(g)
    const int g3 = g & 3;
    const int rho_g = ((g & 15) << 3) | gh;     // rho(g)
    const int n  = blockIdx.x;
    const int Y0 = positions[2 * n];
    const int X0 = positions[2 * n + 1];

    // per-lane constants for the relabeled cross-8 stages
    const float sA = (c < 4) ? 1.0f : -1.0f;
    const float sB = (jc & 2) ? -1.0f : 1.0f;
    const float sC = (jc & 1) ? -1.0f : 1.0f;
    const v2f sAp = {sA, sA}, sBp = {sB, sB}, sCp = {sC, sC};
    const v2f fA  = {FA2_RE[c], FA2_IM[c]};
    const v2f rrf = ((jc & 3) == 3) ? (v2f){0.0f, -1.0f} : (v2f){1.0f, 0.0f};

    // W16 twiddle pairs (compile-time constants, r2-proven codegen)
    const v2f W[8] = {
        { 1.0f,         0.0f        },
        { 0.923879533f, 0.382683432f},
        { 0.707106781f, 0.707106781f},
        { 0.382683432f, 0.923879533f},
        { 0.0f,         1.0f        },
        {-0.382683432f, 0.923879533f},
        {-0.707106781f, 0.707106781f},
        {-0.923879533f, 0.382683432f},
    };

    float fx = (float)(g < 64 ? g : g - 128) * (1.0f / 25.6f);
    float phx = -0.15707963267948966f * fx * fx;
    float pxs, pxc; __sincosf(phx, &pxs, &pxc);
    const v2f px = {pxc, pxs};

    const long long base = (long long)n * NPIX;

    v2f v[16];

    for (int m = 0; m < NMODES; m++) {
        __syncthreads();   // protect LTH reuse across modes
        #pragma unroll
        for (int i = 0; i < 16; i++) {           // ex = probe[m]*patch(slice0)
            int w  = jc + 8 * i;
            int pi = m * NPIX + g * 128 + w;
            v2f pr = {probe_re[pi], probe_im[pi]};
            int oi = (Y0 + g) * OBJW + X0 + w;
            v2f ob = {obj_re[oi], obj_im[oi]};
            v[i] = pk_cmul(pr, ob);
        }

        for (int s = 1; s < NSLICES; s++) {
            pass_A_fwd(v, c, sAp, sBp, sCp, fA, rrf, W);
            {   // T1 write: maj = kw = BR4(p)+16rcp, min = rho_g^rcp
                int b0 = (rcp << 11) + ((rho_g ^ rcp) ^ 0);
                int b1 = (rcp << 11) + ((rho_g ^ rcp) ^ 8);
                int b2 = (rcp << 11) + ((rho_g ^ rcp) ^ 16);
                int b3 = (rcp << 11) + ((rho_g ^ rcp) ^ 24);
                #pragma unroll
                for (int p = 0; p < 16; p++) {
                    const int q = BR4(p) & 3;
                    int bb = (q == 0) ? b0 : (q == 1) ? b1 : (q == 2) ? b2 : b3;
                    LTH[bb + BR4(p) * 128] = toh2(v[p]);
                }
            }
            __syncthreads();
            {   // T1 read: maj = g, min = (jc^gh)+8i
                int r0 = g * 128 + (jc ^ gh) + ((0 ^ g3) << 3);
                int r1 = g * 128 + (jc ^ gh) + ((1 ^ g3) << 3);
                int r2 = g * 128 + (jc ^ gh) + ((2 ^ g3) << 3);
                int r3 = g * 128 + (jc ^ gh) + ((3 ^ g3) << 3);
                #pragma unroll
                for (int i = 0; i < 16; i++) {
                    const int q = i & 3;
                    int bb = (q == 0) ? r0 : (q == 1) ? r1 : (q == 2) ? r2 : r3;
                    v[i] = frh2(LTH[bb + (i & 12) * 8]);
                }
            }
            __syncthreads();
            pass_B_fwd(v, c, sAp, sBp, sCp, fA, rrf, W);
            #pragma unroll                       // * prop
            for (int p = 0; p < 16; p++) {
                v2f pp = pk_cmul(ldv(&PY_C.e[8 * p + c]), px);
                v[p] = pk_cmul(v[p], pp);
            }
            pass_B_inv(v, c, sAp, sBp, sCp, fA, rrf, W);
            {   // T2 write: maj = i+16jc, min = rho_g^jc
                int b0 = (jc << 11) + ((rho_g ^ jc) ^ 0);
                int b1 = (jc << 11) + ((rho_g ^ jc) ^ 8);
                int b2 = (jc << 11) + ((rho_g ^ jc) ^ 16);
                int b3 = (jc << 11) + ((rho_g ^ jc) ^ 24);
                #pragma unroll
                for (int i = 0; i < 16; i++) {
                    const int q = i & 3;
                    int bb = (q == 0) ? b0 : (q == 1) ? b1 : (q == 2) ? b2 : b3;
                    LTH[bb + i * 128] = toh2(v[i]);
                }
            }
            __syncthreads();
            {   // T2 read: maj = g, min = (rcp^gh)+8*BR4(p)
                int r0 = g * 128 + (rcp ^ gh) + ((0 ^ g3) << 3);
                int r1 = g * 128 + (rcp ^ gh) + ((1 ^ g3) << 3);
                int r2 = g * 128 + (rcp ^ gh) + ((2 ^ g3) << 3);
                int r3 = g * 128 + (rcp ^ gh) + ((3 ^ g3) << 3);
                #pragma unroll
                for (int p = 0; p < 16; p++) {
                    const int q = BR4(p) & 3;
                    int bb = (q == 0) ? r0 : (q == 1) ? r1 : (q == 2) ? r2 : r3;
                    v[p] = frh2(LTH[bb + (BR4(p) & 12) * 8]);
                }
            }
            __syncthreads();
            pass_A_inv(v, c, sAp, sBp, sCp, fA, rrf, W);
            #pragma unroll                       // * patch(slice s)
            for (int i = 0; i < 16; i++) {
                int w  = jc + 8 * i;
                int oi = (s * OBJW + Y0 + g) * OBJW + X0 + w;
                v2f ob = {obj_re[oi], obj_im[oi]};
                v[i] = pk_cmul(v[i], ob);
            }
        }

        // final FFT2: Fw, T1, Fh(pass_B), |.|^2 RMW into out
        pass_A_fwd(v, c, sAp, sBp, sCp, fA, rrf, W);
        {
            int b0 = (rcp << 11) + ((rho_g ^ rcp) ^ 0);
            int b1 = (rcp << 11) + ((rho_g ^ rcp) ^ 8);
            int b2 = (rcp << 11) + ((rho_g ^ rcp) ^ 16);
            int b3 = (rcp << 11) + ((rho_g ^ rcp) ^ 24);
            #pragma unroll
            for (int p = 0; p < 16; p++) {
                const int q = BR4(p) & 3;
                int bb = (q == 0) ? b0 : (q == 1) ? b1 : (q == 2) ? b2 : b3;
                LTH[bb + BR4(p) * 128] = toh2(v[p]);
            }
        }
        __syncthreads();
        {
            int r0 = g * 128 + (jc ^ gh) + ((0 ^ g3) << 3);
            int r1 = g * 128 + (jc ^ gh) + ((1 ^ g3) << 3);
            int r2 = g * 128 + (jc ^ gh) + ((2 ^ g3) << 3);
            int r3 = g * 128 + (jc ^ gh) + ((3 ^ g3) << 3);
            #pragma unroll
            for (int i = 0; i < 16; i++) {
                const int q = i & 3;
                int bb = (q == 0) ? r0 : (q == 1) ? r1 : (q == 2) ? r2 : r3;
                v[i] = frh2(LTH[bb + (i & 12) * 8]);
            }
        }
        pass_B_fwd(v, c, sAp, sBp, sCp, fA, rrf, W);
        // fftshift: (kh,kw)->(kh^64,kw^64); kh=rcp+8BR4(p), kw=g.
        #pragma unroll
        for (int p = 0; p < 16; p++) {
            int kh = rcp + 8 * BR4(p);
            long long oidx = base + (long long)(((kh ^ 64) << 7) + (g ^ 64));
            float val = fmaf(v[p].x, v[p].x, v[p].y * v[p].y);
            if (m > 0) val += out[oidx];
            out[oidx] = val;
        }
    }
}

extern "C" void kernel_launch(void* const* d_in, const int* in_sizes, int n_in,
                              void* d_out, int out_size, void* d_ws, size_t ws_size,
                              hipStream_t stream) {
    const float* probe_re = (const float*)d_in[0];
    const float* probe_im = (const float*)d_in[1];
    const float* obj_re   = (const float*)d_in[2];
    const float* obj_im   = (const float*)d_in[3];
    const int*   pos      = (const int*)d_in[4];
    float* out = (float*)d_out;

    const int N = out_size / NPIX;   // 512 positions
    multislice_kernel<<<dim3(N), dim3(NT), 0, stream>>>(
        probe_re, probe_im, obj_re, obj_im, pos, out);
}

// Round 13
// 1203.540 us; speedup vs baseline: 1.5184x; 1.5184x over previous
//
#include <hip/hip_runtime.h>
#include <hip/hip_fp16.h>
#include <math.h>

#define NT      1024
#define NPIX    16384
#define NSLICES 8
#define NMODES  4
#define OBJW    512
#define LSTR    136        // padded major stride (half2 units): 136%32=8

typedef float v2f __attribute__((ext_vector_type(2)));

// ---- packed fp32 complex primitives (VOP3P) --------------------------------
__device__ __forceinline__ v2f pk_add(v2f a, v2f b) {
    v2f d; asm("v_pk_add_f32 %0, %1, %2" : "=v"(d) : "v"(a), "v"(b)); return d;
}
__device__ __forceinline__ v2f pk_sub(v2f a, v2f b) {
    v2f d; asm("v_pk_add_f32 %0, %1, %2 neg_lo:[0,1] neg_hi:[0,1]"
               : "=v"(d) : "v"(a), "v"(b)); return d;
}
__device__ __forceinline__ v2f pk_fma(v2f a, v2f b, v2f c) {
    v2f d; asm("v_pk_fma_f32 %0, %1, %2, %3" : "=v"(d) : "v"(a), "v"(b), "v"(c)); return d;
}
// d = a*b (complex):  t=(ax*bx, ay*bx);  d=(t.x - ay*by, t.y + ax*by)
__device__ __forceinline__ v2f pk_cmul(v2f a, v2f b) {
    v2f t, d;
    asm("v_pk_mul_f32 %0, %1, %2 op_sel:[0,0] op_sel_hi:[1,0]"
        : "=v"(t) : "v"(a), "v"(b));
    asm("v_pk_fma_f32 %0, %1, %2, %3 op_sel:[1,1,0] op_sel_hi:[0,1,1] neg_lo:[1,0,0]"
        : "=v"(d) : "v"(a), "v"(b), "v"(t));
    return d;
}
// d = a*conj(b)
__device__ __forceinline__ v2f pk_cmulc(v2f a, v2f b) {
    v2f t, d;
    asm("v_pk_mul_f32 %0, %1, %2 op_sel:[0,0] op_sel_hi:[1,0]"
        : "=v"(t) : "v"(a), "v"(b));
    asm("v_pk_fma_f32 %0, %1, %2, %3 op_sel:[1,1,0] op_sel_hi:[0,1,1] neg_hi:[1,0,0]"
        : "=v"(d) : "v"(a), "v"(b), "v"(t));
    return d;
}
__device__ __forceinline__ v2f pk_mnegi(v2f a) { return (v2f){a.y, -a.x}; }  // a * -i
__device__ __forceinline__ v2f pk_mposi(v2f a) { return (v2f){-a.y, a.x}; }  // a * +i

// 4-bit reversal (constexpr -> folds to literals in unrolled loops)
__host__ __device__ constexpr int BR4(int p) {
    return ((p & 1) << 3) | ((p & 2) << 1) | ((p & 4) >> 1) | ((p & 8) >> 3);
}
__host__ __device__ constexpr int BR3(int c) {
    return ((c & 1) << 2) | (c & 2) | ((c & 4) >> 2);
}

// ---- lane exchange primitives: ALL DPP (full-rate VALU, zero LDS pipe) -----
// Affine relabel j<4->j, j>=4->11-j turns the DFT8 exchanges (4,2,1) into
// (7,2,1): xor7 = ROW_HALF_MIRROR (0x141), xor2/xor1 = quad_perm.
__device__ __forceinline__ float xor1f(float x) {
    int i = __float_as_int(x);
    return __int_as_float(__builtin_amdgcn_update_dpp(i, i, 0xB1, 0xF, 0xF, false));
}
__device__ __forceinline__ float xor2f(float x) {
    int i = __float_as_int(x);
    return __int_as_float(__builtin_amdgcn_update_dpp(i, i, 0x4E, 0xF, 0xF, false));
}
__device__ __forceinline__ float xor7f(float x) {
    int i = __float_as_int(x);
    return __int_as_float(__builtin_amdgcn_update_dpp(i, i, 0x141, 0xF, 0xF, false));
}

// relabeled stage-A twiddle fA'(lane) = lane<4 ? 1 : W8^(j(lane)-4) = W8^(7-lane)
__device__ __constant__ float FA2_RE[8] = {1,1,1,1, -0.707106781f,  0.0f, 0.707106781f, 1.0f};
__device__ __constant__ float FA2_IM[8] = {0,0,0,0, -0.707106781f, -1.0f,-0.707106781f, 0.0f};

// ---- local 16-point FFT in registers (r2-proven codegen) -------------------
__device__ __forceinline__ void fft16_fwd(v2f v[16], const v2f* W) {
    #pragma unroll
    for (int s = 8; s >= 1; s >>= 1) {
        #pragma unroll
        for (int q = 0; q < 16; q += 2 * s) {
            #pragma unroll
            for (int j = 0; j < s; j++) {
                const int tw = j * (8 / s);
                v2f u = v[q + j], w = v[q + j + s];
                v[q + j] = pk_add(u, w);
                v2f d = pk_sub(u, w);
                v[q + j + s] = (tw == 0) ? d
                             : (tw == 4) ? pk_mnegi(d)
                                         : pk_cmulc(d, W[tw]);
            }
        }
    }
}
__device__ __forceinline__ void fft16_inv(v2f v[16], const v2f* W) {
    #pragma unroll
    for (int s = 1; s <= 8; s <<= 1) {
        #pragma unroll
        for (int q = 0; q < 16; q += 2 * s) {
            #pragma unroll
            for (int j = 0; j < s; j++) {
                const int tw = j * (8 / s);
                v2f u = v[q + j], w = v[q + j + s];
                v2f tv = (tw == 0) ? w
                       : (tw == 4) ? pk_mposi(w)
                                   : pk_cmul(w, W[tw]);
                v[q + j]     = pk_add(u, tv);
                v[q + j + s] = pk_sub(u, tv);
            }
        }
    }
}

// ---- cross-thread DFT8 over logical j (exchanges xor7, xor2, xor1) ---------
__device__ __forceinline__ void cross8_fwd(v2f v[16], v2f sAp, v2f sBp, v2f sCp,
                                           v2f fA, v2f rrf) {
    #pragma unroll
    for (int p = 0; p < 16; p++) {
        v2f o;
        o.x = xor7f(v[p].x); o.y = xor7f(v[p].y);
        v2f a = pk_fma(sAp, v[p], o);
        v2f b = pk_cmul(a, fA);
        o.x = xor2f(b.x); o.y = xor2f(b.y);
        v2f n = pk_fma(sBp, b, o);
        v2f r = pk_cmul(n, rrf);
        o.x = xor1f(r.x); o.y = xor1f(r.y);
        v[p] = pk_fma(sCp, r, o);
    }
}
__device__ __forceinline__ void cross8_inv(v2f v[16], v2f sAp, v2f sBp, v2f sCp,
                                           v2f fA, v2f rrf) {
    #pragma unroll
    for (int p = 0; p < 16; p++) {
        v2f o;
        o.x = xor1f(v[p].x); o.y = xor1f(v[p].y);
        v2f n = pk_fma(sCp, v[p], o);
        v2f r = pk_cmulc(n, rrf);
        o.x = xor2f(r.x); o.y = xor2f(r.y);
        v2f b = pk_fma(sBp, r, o);
        v2f a = pk_cmulc(b, fA);
        o.x = xor7f(a.x); o.y = xor7f(a.y);
        v[p] = pk_fma(sAp, a, o);
    }
}

// ---- pass A (local-first): input reg i = elem jc+8i; out reg p = BR4(p)+16rcp
__device__ __forceinline__ void pass_A_fwd(v2f v[16], int c, v2f sAp, v2f sBp,
                                           v2f sCp, v2f fA, v2f rrf,
                                           const v2f* W, const v2f* tA) {
    fft16_fwd(v, W);
    #pragma unroll
    for (int p = 0; p < 16; p++) v[p] = pk_cmul(v[p], tA[8 * p + c]);
    cross8_fwd(v, sAp, sBp, sCp, fA, rrf);
}
__device__ __forceinline__ void pass_A_inv(v2f v[16], int c, v2f sAp, v2f sBp,
                                           v2f sCp, v2f fA, v2f rrf,
                                           const v2f* W, const v2f* tA) {
    cross8_inv(v, sAp, sBp, sCp, fA, rrf);
    #pragma unroll
    for (int p = 0; p < 16; p++) v[p] = pk_cmulc(v[p], tA[8 * p + c]);
    fft16_inv(v, W);
}

// ---- pass B (cross-first): input reg i = row i+16*jc
__device__ __forceinline__ void pass_B_fwd(v2f v[16], int c, v2f sAp, v2f sBp,
                                           v2f sCp, v2f fA, v2f rrf,
                                           const v2f* W, const v2f* tB) {
    cross8_fwd(v, sAp, sBp, sCp, fA, rrf);
    #pragma unroll
    for (int i = 0; i < 16; i++) v[i] = pk_cmul(v[i], tB[8 * i + c]);
    fft16_fwd(v, W);
}
__device__ __forceinline__ void pass_B_inv(v2f v[16], int c, v2f sAp, v2f sBp,
                                           v2f sCp, v2f fA, v2f rrf,
                                           const v2f* W, const v2f* tB) {
    fft16_inv(v, W);
    #pragma unroll
    for (int i = 0; i < 16; i++) v[i] = pk_cmulc(v[i], tB[8 * i + c]);
    cross8_inv(v, sAp, sBp, sCp, fA, rrf);
}

// ---- conversions -----------------------------------------------------------
__device__ __forceinline__ __half2 toh2(v2f a) {
    return __float22half2_rn(make_float2(a.x, a.y));
}
__device__ __forceinline__ v2f frh2(__half2 h) {
    float2 f = __half22float2(h);
    return (v2f){f.x, f.y};
}

// ---- main kernel: r9 verified optimum (1212 us) ----------------------------
// Structure: 1024 threads, 1 row/thread, single 69.6KB transpose buffer,
// 4 barriers/slice, all-DPP cross8 (zero ds_swizzle on the butterfly chain),
// packed VOP3P complex math, LDS twiddle tables, conflict-free XOR/rho layout.
// Session-closed levers: 2 WGs/CU categorical wall (r3/r4/r5/r10/r12);
// barrier reduction neutral (r7); per-thread ILP spills at the 64-VGPR cap
// (r3/r8); swizzled-addressing/constant tables spill (r12).
__global__ void
__attribute__((amdgpu_flat_work_group_size(1024, 1024)))
multislice_kernel(const float* __restrict__ probe_re,
                  const float* __restrict__ probe_im,
                  const float* __restrict__ obj_re,
                  const float* __restrict__ obj_im,
                  const int*   __restrict__ positions,
                  float*       __restrict__ out)
{
    __shared__ __half2 LTH[128 * LSTR];   // 69632 B transpose buffer (fp16)
    __shared__ v2f     tA[128];           // pass-A twiddle [8p+c], baked with jc
    __shared__ v2f     tB[128];           // pass-B twiddle [8i+c], baked with rcp
    __shared__ v2f     pytp[128];         // prop y-factor/16384, kh=rcp+8BR4(p)

    const int t  = threadIdx.x;
    const int g  = t >> 3;                      // row (R) / col (C) index
    const int c  = t & 7;
    const int jc  = (c < 4) ? c : 11 - c;       // logical sub-index this lane holds
    const int rcp = BR3(jc);                    // frequency sub-index after cross8
    const int gh = g >> 4;                      // sigma(g)
    const int rho_g = ((g & 15) << 3) | gh;     // rho(g)
    const int n  = blockIdx.x;
    const int Y0 = positions[2 * n];
    const int X0 = positions[2 * n + 1];

    if (t < 128) {
        int p_ = t >> 3, c_ = t & 7;
        int jc_  = (c_ < 4) ? c_ : 11 - c_;
        int rcp_ = BR3(jc_);
        float angA = -2.0f * 3.14159265358979323846f
                     * (float)(jc_ * BR4(p_)) / 128.0f;
        float s, cc; __sincosf(angA, &s, &cc);
        tA[t] = (v2f){cc, s};
        float angB = -2.0f * 3.14159265358979323846f
                     * (float)(p_ * rcp_) / 128.0f;
        __sincosf(angB, &s, &cc);
        tB[t] = (v2f){cc, s};
        int kh = rcp_ + 8 * BR4(p_);
        float fy = (float)(kh < 64 ? kh : kh - 128) * (1.0f / 25.6f);
        float ph = -0.15707963267948966f * fy * fy;
        float ps, pcs; __sincosf(ph, &ps, &pcs);
        pytp[t] = (v2f){pcs * (1.0f / 16384.0f), ps * (1.0f / 16384.0f)};
    }

    // per-lane constants for the relabeled cross-8 stages (phi-conjugates)
    const float sA = (c < 4) ? 1.0f : -1.0f;    // j<4 <=> lane<4
    const float sB = (jc & 2) ? -1.0f : 1.0f;
    const float sC = (jc & 1) ? -1.0f : 1.0f;
    const v2f sAp = {sA, sA}, sBp = {sB, sB}, sCp = {sC, sC};
    const v2f fA  = {FA2_RE[c], FA2_IM[c]};
    const v2f rrf = ((jc & 3) == 3) ? (v2f){0.0f, -1.0f} : (v2f){1.0f, 0.0f};

    // W16 twiddle pairs (compile-time constants, r2-proven codegen)
    const v2f W[8] = {
        { 1.0f,         0.0f        },
        { 0.923879533f, 0.382683432f},
        { 0.707106781f, 0.707106781f},
        { 0.382683432f, 0.923879533f},
        { 0.0f,         1.0f        },
        {-0.382683432f, 0.923879533f},
        {-0.707106781f, 0.707106781f},
        {-0.923879533f, 0.382683432f},
    };

    float fx = (float)(g < 64 ? g : g - 128) * (1.0f / 25.6f);
    float phx = -0.15707963267948966f * fx * fx;
    float pxs, pxc; __sincosf(phx, &pxs, &pxc);
    const v2f px = {pxc, pxs};
    __syncthreads();

    const long long base = (long long)n * NPIX;
    // precomputed transpose address bases (re-baked with jc/rcp)
    const int a1w = rho_g ^ rcp;                   // T1-write minor
    const int a1r = g * LSTR + (jc ^ gh);          // T1-read base (+ 8i)
    const int a2w = rho_g ^ jc;                    // T2-write minor
    const int a2r = g * LSTR + (rcp ^ gh);         // T2-read base (+ 8*BR4(p))

    v2f v[16];

    for (int m = 0; m < NMODES; m++) {
        __syncthreads();   // protect LTH reuse across modes
        #pragma unroll
        for (int i = 0; i < 16; i++) {           // ex = probe[m]*patch(slice0)
            int w  = jc + 8 * i;
            int pi = m * NPIX + g * 128 + w;
            v2f pr = {probe_re[pi], probe_im[pi]};
            int oi = (Y0 + g) * OBJW + X0 + w;
            v2f ob = {obj_re[oi], obj_im[oi]};
            v[i] = pk_cmul(pr, ob);
        }

        for (int s = 1; s < NSLICES; s++) {
            pass_A_fwd(v, c, sAp, sBp, sCp, fA, rrf, W, tA);
            #pragma unroll                       // T1 write [kw][r=g]
            for (int p = 0; p < 16; p++) {
                int kw = BR4(p) + 16 * rcp;
                LTH[kw * LSTR + a1w] = toh2(v[p]);
            }
            __syncthreads();
            #pragma unroll                       // T1 read -> C: reg i = row i+16jc
            for (int i = 0; i < 16; i++)
                v[i] = frh2(LTH[a1r + 8 * i]);
            __syncthreads();
            pass_B_fwd(v, c, sAp, sBp, sCp, fA, rrf, W, tB);
            #pragma unroll                       // * prop
            for (int p = 0; p < 16; p++) {
                v2f pp = pk_cmul(pytp[8 * p + c], px);
                v[p] = pk_cmul(v[p], pp);
            }
            pass_B_inv(v, c, sAp, sBp, sCp, fA, rrf, W, tB);
            #pragma unroll                       // T2 write [r=i+16jc][g]
            for (int i = 0; i < 16; i++)
                LTH[(i + 16 * jc) * LSTR + a2w] = toh2(v[i]);
            __syncthreads();
            #pragma unroll                       // T2 read -> R: reg p = kw
            for (int p = 0; p < 16; p++)
                v[p] = frh2(LTH[a2r + 8 * BR4(p)]);
            __syncthreads();
            pass_A_inv(v, c, sAp, sBp, sCp, fA, rrf, W, tA);
            #pragma unroll                       // * patch(slice s)
            for (int i = 0; i < 16; i++) {
                int w  = jc + 8 * i;
                int oi = (s * OBJW + Y0 + g) * OBJW + X0 + w;
                v2f ob = {obj_re[oi], obj_im[oi]};
                v[i] = pk_cmul(v[i], ob);
            }
        }

        // final FFT2: Fw, T1, Fh(pass_B), |.|^2 RMW into out
        pass_A_fwd(v, c, sAp, sBp, sCp, fA, rrf, W, tA);
        #pragma unroll
        for (int p = 0; p < 16; p++) {
            int kw = BR4(p) + 16 * rcp;
            LTH[kw * LSTR + a1w] = toh2(v[p]);
        }
        __syncthreads();
        #pragma unroll
        for (int i = 0; i < 16; i++)
            v[i] = frh2(LTH[a1r + 8 * i]);
        pass_B_fwd(v, c, sAp, sBp, sCp, fA, rrf, W, tB);
        // fftshift: (kh,kw)->(kh^64,kw^64); kh=rcp+8BR4(p), kw=g.
        // Same thread owns the same slots every mode -> plain RMW, no race.
        #pragma unroll
        for (int p = 0; p < 16; p++) {
            int kh = rcp + 8 * BR4(p);
            long long oidx = base + (long long)(((kh ^ 64) << 7) + (g ^ 64));
            float val = fmaf(v[p].x, v[p].x, v[p].y * v[p].y);
            if (m > 0) val += out[oidx];
            out[oidx] = val;
        }
    }
}

extern "C" void kernel_launch(void* const* d_in, const int* in_sizes, int n_in,
                              void* d_out, int out_size, void* d_ws, size_t ws_size,
                              hipStream_t stream) {
    const float* probe_re = (const float*)d_in[0];
    const float* probe_im = (const float*)d_in[1];
    const float* obj_re   = (const float*)d_in[2];
    const float* obj_im   = (const float*)d_in[3];
    const int*   pos      = (const int*)d_in[4];
    float* out = (float*)d_out;

    const int N = out_size / NPIX;   // 512 positions
    multislice_kernel<<<dim3(N), dim3(NT), 0, stream>>>(
        probe_re, probe_im, obj_re, obj_im, pos, out);
}